// Round 1
// 518.907 us; speedup vs baseline: 1.0118x; 1.0118x over previous
//
#include <hip/hip_runtime.h>

typedef __attribute__((ext_vector_type(8))) short short8;
typedef __attribute__((ext_vector_type(4))) float f32x4;
typedef __attribute__((ext_vector_type(4))) unsigned short ushort4v;
typedef __attribute__((ext_vector_type(4))) unsigned int uint4v;
typedef unsigned short ushort;
typedef unsigned int uint;

#define B_  4
#define L_  8192
#define D_  512
#define H_  8
#define F_  65      // DK + PD
#define CF_ 520     // H * F
#define CFP_ 544    // CF padded to multiple of 32 (MFMA K)
#define KVS_ 80     // K/V head-major row stride (65 used + 15 pad)
#define EPS_ 1e-5f

// fp32 -> bf16 round-to-nearest-even
__device__ __forceinline__ ushort f2b(float f) {
    uint x = __float_as_uint(f);
    uint r = (x + 0x7FFFu + ((x >> 16) & 1u)) >> 16;
    return (ushort)r;
}
__device__ __forceinline__ float b2f(ushort u) {
    return __uint_as_float(((uint)u) << 16);
}

#define GLD16(gptr, sptr) \
    __builtin_amdgcn_global_load_lds((const __attribute__((address_space(1))) void*)(gptr), \
                                     (__attribute__((address_space(3))) void*)(sptr), 16, 0, 0)

// ---------------- K0: cast Wq/Wk/Wv to bf16 ----------------
__global__ __launch_bounds__(256)
void cast_w(const float* __restrict__ Wq, const float* __restrict__ Wk,
            const float* __restrict__ Wv, ushort* __restrict__ Wb)
{
    const int i = blockIdx.x * 256 + threadIdx.x;
    const int z = i >> 16;
    const float* __restrict__ src = (z == 0) ? Wq : (z == 1) ? Wk : Wv;
    const int o = (i & 65535) * 4;
    const float4 f = *(const float4*)&src[o];
    ushort4v v;
    v.x = f2b(f.x); v.y = f2b(f.y); v.z = f2b(f.z); v.w = f2b(f.w);
    *(ushort4v*)&Wb[(size_t)z * 262144 + o] = v;
}

// ---------------- K1: MFMA projection GEMM + fused LN/pos epilogue ----------------
// A operand (fp32 X) is now staged to LDS via async global_load_lds (linear LDS
// dest, XOR-pre-swizzled global source so fragment reads are bank-conflict-free),
// and converted to bf16 in the fragment-read phase with v_cvt_pk_bf16_f32 (RNE,
// bit-identical to f2b). Removes the serial load->cvt->ds_write chain per K-step.
__global__ __launch_bounds__(256, 2)
void proj_mfma(const float* __restrict__ Xq, const float* __restrict__ Xk,
               const float* __restrict__ Xv, const ushort* __restrict__ Wb,
               const float* __restrict__ bq, const float* __restrict__ bk,
               const float* __restrict__ bv, const float* __restrict__ pos,
               const float* __restrict__ gK, const float* __restrict__ betaK,
               const float* __restrict__ gV, const float* __restrict__ betaV,
               ushort* __restrict__ Qc, ushort* __restrict__ Kh,
               ushort* __restrict__ Vh)
{
    const int x  = blockIdx.x;
    const int m0 = (((x >> 5) << 3) + (x & 7)) * 128;   // XCD swizzle: same-m n-tiles
    const int n0 = ((x >> 3) & 3) * 128;                // land on same XCD, ids 8 apart
    const int z  = blockIdx.y;

    const float*  __restrict__ X    = (z == 0) ? Xq : (z == 1) ? Xk : Xv;
    const ushort* __restrict__ W    = Wb + (size_t)z * 262144;
    const float*  __restrict__ bias = (z == 0) ? bq : (z == 1) ? bk : bv;

    const int t  = threadIdx.x;
    const int w  = t >> 6, l = t & 63;
    const int wm = (w >> 1) * 64, wn = (w & 1) * 64;
    const int lg = l >> 4, lm = l & 15;

    __shared__ __align__(16) float sAf[4096];   // 128 rows x 32 k fp32, 16 KB, swizzled 16B slots
    __shared__ __align__(16) short sB[4096];    // 128 rows x 32 k bf16, 8 KB

    f32x4 acc[4][4];
#pragma unroll
    for (int i = 0; i < 4; ++i)
#pragma unroll
        for (int j = 0; j < 4; ++j) acc[i][j] = (f32x4){0.f, 0.f, 0.f, 0.f};

    // A staging: per wave-instr, 64 lanes x 16B fill 8 rows (128B each) linearly.
    // LDS slot s of row r holds global half-chunk h = s ^ (r&7)  (pre-swizzled source).
    const int lr = l >> 3;                 // row-within-8 for this lane
    const int hg = (l & 7) ^ lr;           // global half-chunk this lane fetches
    const float* ag[4];
    float* al[4];
#pragma unroll
    for (int i = 0; i < 4; ++i) {
        const int row = (w * 4 + i) * 8 + lr;
        ag[i] = &X[(size_t)(m0 + row) * D_ + hg * 4];
        al[i] = &sAf[(w * 4 + i) * 256];   // wave-uniform 1KB chunk base
    }

    const ushort* bsrc0 = &W[(size_t)(n0 + l) * D_ + w * 8];
    const ushort* bsrc1 = &W[(size_t)(n0 + 64 + l) * D_ + w * 8];
    short* bl0 = &sB[(w * 128) * 8];
    short* bl1 = &sB[(w * 128 + 64) * 8];

    // A fragment reads: row r, logical half-chunks lg*2 and lg*2+1 -> slots XOR (r&7).
    const float* ar0[4]; const float* ar1[4];
    const short* br[4];
#pragma unroll
    for (int i = 0; i < 4; ++i) {
        const int r = wm + i * 16 + lm;
        ar0[i] = &sAf[r * 32 + (((lg * 2)     ^ (r & 7)) * 4)];
        ar1[i] = &sAf[r * 32 + (((lg * 2 + 1) ^ (r & 7)) * 4)];
        br[i]  = &sB[(lg * 128 + wn + i * 16 + lm) * 8];
    }

    for (int k0 = 0; k0 < D_; k0 += 32) {
#pragma unroll
        for (int i = 0; i < 4; ++i) GLD16(ag[i] + k0, al[i]);
        GLD16(bsrc0 + k0, bl0);
        GLD16(bsrc1 + k0, bl1);

        __syncthreads();

        short8 af[4], bfv[4];
#pragma unroll
        for (int i = 0; i < 4; ++i) {
            const f32x4 a0 = *(const f32x4*)ar0[i];
            const f32x4 a1 = *(const f32x4*)ar1[i];
            uint u0, u1, u2, u3;
            asm("v_cvt_pk_bf16_f32 %0, %1, %2" : "=v"(u0) : "v"(a0[0]), "v"(a0[1]));
            asm("v_cvt_pk_bf16_f32 %0, %1, %2" : "=v"(u1) : "v"(a0[2]), "v"(a0[3]));
            asm("v_cvt_pk_bf16_f32 %0, %1, %2" : "=v"(u2) : "v"(a1[0]), "v"(a1[1]));
            asm("v_cvt_pk_bf16_f32 %0, %1, %2" : "=v"(u3) : "v"(a1[2]), "v"(a1[3]));
            union { uint4v u4; short8 s8; } cv;
            cv.u4 = (uint4v){u0, u1, u2, u3};
            af[i]  = cv.s8;
            bfv[i] = *(const short8*)br[i];
        }
#pragma unroll
        for (int mt = 0; mt < 4; ++mt)
#pragma unroll
            for (int nt = 0; nt < 4; ++nt)
                acc[mt][nt] = __builtin_amdgcn_mfma_f32_16x16x32_bf16(
                    af[mt], bfv[nt], acc[mt][nt], 0, 0, 0);

        __syncthreads();
    }

    // -------- fused epilogue --------
    const int h = (n0 >> 6) + (w & 1);   // this wave's head (wave owns 64 rows x 64 head-cols)
    float bvv[4];
#pragma unroll
    for (int nt = 0; nt < 4; ++nt) bvv[nt] = bias[n0 + wn + nt * 16 + lm];

    if (z == 0) {
#pragma unroll
        for (int mt = 0; mt < 4; ++mt) {
#pragma unroll
            for (int r = 0; r < 4; ++r) {
                const int m = m0 + wm + mt * 16 + lg * 4 + r;
                ushort* orow = Qc + (size_t)m * CFP_ + h * F_;
#pragma unroll
                for (int nt = 0; nt < 4; ++nt)
                    orow[1 + nt * 16 + lm] = f2b(acc[mt][nt][r] + bvv[nt]);
                if (lm == 15) orow[0] = f2b(pos[m]);
                if (h == 7 && lm < 12) *(uint*)&Qc[(size_t)m * CFP_ + CF_ + 2 * lm] = 0u;
            }
        }
    } else {
        const float* gp = (z == 1) ? gK : gV;
        const float* bp = (z == 1) ? betaK : betaV;
        ushort* Oh = (z == 1) ? Kh : Vh;
        float gg[4], bb2[4];
#pragma unroll
        for (int nt = 0; nt < 4; ++nt) {
            gg[nt]  = gp[h * 64 + nt * 16 + lm];
            bb2[nt] = bp[h * 64 + nt * 16 + lm];
        }
#pragma unroll
        for (int mt = 0; mt < 4; ++mt) {
#pragma unroll
            for (int r = 0; r < 4; ++r) {
                float v0 = acc[mt][0][r] + bvv[0];
                float v1 = acc[mt][1][r] + bvv[1];
                float v2 = acc[mt][2][r] + bvv[2];
                float v3 = acc[mt][3][r] + bvv[3];
                float s = v0 + v1 + v2 + v3;
                float q = v0 * v0 + v1 * v1 + v2 * v2 + v3 * v3;
                s += __shfl_xor(s, 1); s += __shfl_xor(s, 2);
                s += __shfl_xor(s, 4); s += __shfl_xor(s, 8);
                q += __shfl_xor(q, 1); q += __shfl_xor(q, 2);
                q += __shfl_xor(q, 4); q += __shfl_xor(q, 8);
                const float mean = s * (1.f / 64.f);
                const float var = q * (1.f / 64.f) - mean * mean;
                const float rs = rsqrtf(var + EPS_);
                const int m = m0 + wm + mt * 16 + lg * 4 + r;
                const int bb = m >> 13, ll = m & 8191;
                ushort* row = Oh + ((size_t)(bb * H_ + h) * L_ + ll) * KVS_;
                row[1 + 0 * 16 + lm] = f2b((v0 - mean) * rs * gg[0] + bb2[0]);
                row[1 + 1 * 16 + lm] = f2b((v1 - mean) * rs * gg[1] + bb2[1]);
                row[1 + 2 * 16 + lm] = f2b((v2 - mean) * rs * gg[2] + bb2[2]);
                row[1 + 3 * 16 + lm] = f2b((v3 - mean) * rs * gg[3] + bb2[3]);
                if (lm == 15) row[0] = f2b(pos[m]);
                else          row[F_ + lm] = 0;   // cols 65..79 zero
            }
        }
    }
}

// ---------------- K3: attn accumulation: sum_l K[l][d]*V[l][e] ----------------
__global__ __launch_bounds__(256)
void attn_accum(const ushort* __restrict__ Kh, const ushort* __restrict__ Vh,
                float* __restrict__ attn_acc)
{
    const int s = blockIdx.x;   // 512-l slice, 0..15
    const int h = blockIdx.y;
    const int b = blockIdx.z;
    const int t = threadIdx.x;

    __shared__ __align__(16) float Ks[64][84];
    __shared__ __align__(16) float Vs[64][84];

    const size_t base = ((size_t)(b * H_ + h) * L_ + s * 512) * KVS_;

    float acc[5][5];
#pragma unroll
    for (int i = 0; i < 5; ++i)
#pragma unroll
        for (int j = 0; j < 5; ++j) acc[i][j] = 0.f;

    const int dg = t / 13, eg = t % 13;
    const bool act = (t < 169);
    const int d0 = dg * 5, e0 = eg * 5;

    for (int c = 0; c < 8; ++c) {
#pragma unroll
        for (int i = 0; i < 3; ++i) {
            const int slot = t + i * 256;
            if (slot < 640) {
                const int r = slot / 10;
                const int cc = (slot - r * 10) * 8;
                const size_t g = base + (size_t)(c * 64 + r) * KVS_ + cc;
                const short8 kv = *(const short8*)(const void*)&Kh[g];
                const short8 vv = *(const short8*)(const void*)&Vh[g];
                float* kd = &Ks[r][cc];
                float* vd = &Vs[r][cc];
#pragma unroll
                for (int e = 0; e < 8; ++e) {
                    kd[e] = b2f((ushort)kv[e]);
                    vd[e] = b2f((ushort)vv[e]);
                }
            }
        }
        __syncthreads();
        if (act) {
#pragma unroll 2
            for (int l = 0; l < 64; ++l) {
                float kf[5], vf[5];
#pragma unroll
                for (int i = 0; i < 5; ++i) kf[i] = Ks[l][d0 + i];
#pragma unroll
                for (int j = 0; j < 5; ++j) vf[j] = Vs[l][e0 + j];
#pragma unroll
                for (int i = 0; i < 5; ++i)
#pragma unroll
                    for (int j = 0; j < 5; ++j)
                        acc[i][j] = fmaf(kf[i], vf[j], acc[i][j]);
            }
        }
        __syncthreads();
    }

    if (act) {
        float* dst = attn_acc + (size_t)(b * H_ + h) * (F_ * F_);
#pragma unroll
        for (int i = 0; i < 5; ++i)
#pragma unroll
            for (int j = 0; j < 5; ++j)
                atomicAdd(&dst[(d0 + i) * F_ + (e0 + j)], acc[i][j]);
    }
}

// ---------------- K4: attn/L -> d_out; Gt[b][n][k] = (attn @ fcW_h^T)^T bf16 ----------------
__global__ __launch_bounds__(256)
void attn_fin_G(const float* __restrict__ attn_acc, const float* __restrict__ fcW,
                float* __restrict__ attn_out, ushort* __restrict__ Gt)
{
    const int nc = blockIdx.x;
    const int h = blockIdx.y;
    const int b = blockIdx.z;
    const int t = threadIdx.x;

    __shared__ float S[F_][F_];
    __shared__ float Wl[64][F_];

    const float inv = 1.0f / (float)L_;
    const float* __restrict__ src = attn_acc + (size_t)(b * H_ + h) * F_ * F_;
    for (int idx = t; idx < F_ * F_; idx += 256) {
        const float v = src[idx] * inv;
        S[idx / F_][idx % F_] = v;
        if (nc == 0) attn_out[(size_t)(b * H_ + h) * F_ * F_ + idx] = v;
    }
    for (int idx = t; idx < 64 * F_; idx += 256) {
        const int j = idx / F_;
        const int e = idx - j * F_;
        Wl[j][e] = fcW[(size_t)(nc * 64 + j) * CF_ + h * F_ + e];
    }
    __syncthreads();

    for (int idx = t; idx < F_ * 64; idx += 256) {
        const int d = idx >> 6;
        const int j = idx & 63;
        float g = 0.f;
#pragma unroll 5
        for (int e = 0; e < F_; ++e) g = fmaf(S[d][e], Wl[j][e], g);
        Gt[((size_t)b * 512 + nc * 64 + j) * CFP_ + h * F_ + d] = f2b(g);
    }
    if (h == 7) {
        for (int i2 = t; i2 < 64 * 24; i2 += 256) {
            const int j = i2 / 24;
            const int k = CF_ + (i2 % 24);
            Gt[((size_t)b * 512 + nc * 64 + j) * CFP_ + k] = 0;
        }
    }
}

// ---------------- K5: att_output = Qc @ Gt^T + fcb ----------------
__global__ __launch_bounds__(256, 2)
void out_mfma(const ushort* __restrict__ Qc, const ushort* __restrict__ Gt,
              const float* __restrict__ fcb, float* __restrict__ out)
{
    const int x  = blockIdx.x;
    const int m0 = (((x >> 5) << 3) + (x & 7)) * 128;
    const int n0 = ((x >> 3) & 3) * 128;
    const int b  = blockIdx.z;
    const int t  = threadIdx.x;
    const int w  = t >> 6, l = t & 63;
    const int wm = (w >> 1) * 64, wn = (w & 1) * 64;
    const int lg = l >> 4, lm = l & 15;

    __shared__ __align__(16) short sA[4096];
    __shared__ __align__(16) short sB[4096];

    f32x4 acc[4][4];
#pragma unroll
    for (int i = 0; i < 4; ++i)
#pragma unroll
        for (int j = 0; j < 4; ++j) acc[i][j] = (f32x4){0.f, 0.f, 0.f, 0.f};

    const ushort* A  = Qc + (size_t)(b * L_ + m0) * CFP_;
    const ushort* Bm = Gt + ((size_t)b * 512 + n0) * CFP_;

    const ushort* asrc0 = A + (size_t)l * CFP_ + w * 8;
    const ushort* asrc1 = A + (size_t)(64 + l) * CFP_ + w * 8;
    const ushort* bsrc0 = Bm + (size_t)l * CFP_ + w * 8;
    const ushort* bsrc1 = Bm + (size_t)(64 + l) * CFP_ + w * 8;
    short* al0 = &sA[(w * 128) * 8];
    short* al1 = &sA[(w * 128 + 64) * 8];
    short* bl0 = &sB[(w * 128) * 8];
    short* bl1 = &sB[(w * 128 + 64) * 8];

    const short* ar[4]; const short* br[4];
#pragma unroll
    for (int i = 0; i < 4; ++i) {
        ar[i] = &sA[(lg * 128 + wm + i * 16 + lm) * 8];
        br[i] = &sB[(lg * 128 + wn + i * 16 + lm) * 8];
    }

    for (int k0 = 0; k0 < CFP_; k0 += 32) {
        GLD16(asrc0 + k0, al0);
        GLD16(asrc1 + k0, al1);
        GLD16(bsrc0 + k0, bl0);
        GLD16(bsrc1 + k0, bl1);

        __syncthreads();

        short8 af[4], bfv[4];
#pragma unroll
        for (int i = 0; i < 4; ++i) {
            af[i]  = *(const short8*)ar[i];
            bfv[i] = *(const short8*)br[i];
        }
#pragma unroll
        for (int mt = 0; mt < 4; ++mt)
#pragma unroll
            for (int nt = 0; nt < 4; ++nt)
                acc[mt][nt] = __builtin_amdgcn_mfma_f32_16x16x32_bf16(
                    af[mt], bfv[nt], acc[mt][nt], 0, 0, 0);

        __syncthreads();
    }

    float bvv[4];
#pragma unroll
    for (int nt = 0; nt < 4; ++nt) bvv[nt] = fcb[n0 + wn + nt * 16 + lm];

#pragma unroll
    for (int mt = 0; mt < 4; ++mt) {
#pragma unroll
        for (int r = 0; r < 4; ++r) {
            const int row = m0 + wm + mt * 16 + lg * 4 + r;
            float* orow = out + ((size_t)b * L_ + row) * D_;
#pragma unroll
            for (int nt = 0; nt < 4; ++nt)
                orow[n0 + wn + nt * 16 + lm] = acc[mt][nt][r] + bvv[nt];
        }
    }
}

extern "C" void kernel_launch(void* const* d_in, const int* in_sizes, int n_in,
                              void* d_out, int out_size, void* d_ws, size_t ws_size,
                              hipStream_t stream)
{
    const float* query = (const float*)d_in[0];
    const float* key   = (const float*)d_in[1];
    const float* value = (const float*)d_in[2];
    const float* pos   = (const float*)d_in[3];
    const float* Wq    = (const float*)d_in[4];
    const float* bq    = (const float*)d_in[5];
    const float* Wk    = (const float*)d_in[6];
    const float* bk    = (const float*)d_in[7];
    const float* Wv    = (const float*)d_in[8];
    const float* bv    = (const float*)d_in[9];
    const float* gK    = (const float*)d_in[10];
    const float* betaK = (const float*)d_in[11];
    const float* gV    = (const float*)d_in[12];
    const float* betaV = (const float*)d_in[13];
    const float* fcW   = (const float*)d_in[14];
    const float* fcb   = (const float*)d_in[15];

    char* ws = (char*)d_ws;
    ushort* Qc       = (ushort*)(ws + 0);            // [32768][544] bf16
    ushort* Kh       = (ushort*)(ws + 35651584);     // [4][8][8192][80] bf16
    ushort* Vh       = (ushort*)(ws + 77594624);     // [4][8][8192][80] bf16
    ushort* Wb       = (ushort*)(ws + 119537664);    // [3][512][512] bf16
    float*  attn_acc = (float*) (ws + 121110528);    // [4][8][65][65] fp32
    ushort* Gt       = (ushort*)(ws + 121651328);    // [4][512][544] bf16

    float* att_out  = (float*)d_out;                 // [4][8192][512]
    float* attn_out = att_out + 16777216;            // [4][8][65][65]

    hipMemsetAsync(attn_acc, 0, (size_t)135200 * sizeof(float), stream);

    cast_w<<<dim3(768), 256, 0, stream>>>(Wq, Wk, Wv, Wb);

    proj_mfma<<<dim3(1024, 3), 256, 0, stream>>>(
        query, key, value, Wb, bq, bk, bv, pos,
        gK, betaK, gV, betaV, Qc, Kh, Vh);

    attn_accum<<<dim3(16, 8, 4), 256, 0, stream>>>(Kh, Vh, attn_acc);

    attn_fin_G<<<dim3(8, 8, 4), 256, 0, stream>>>(attn_acc, fcW, attn_out, Gt);

    out_mfma<<<dim3(256, 1, 4), 256, 0, stream>>>(Qc, Gt, fcb, att_out);
}

// Round 3
// 498.797 us; speedup vs baseline: 1.0526x; 1.0403x over previous
//
#include <hip/hip_runtime.h>

typedef __attribute__((ext_vector_type(8))) short short8;
typedef __attribute__((ext_vector_type(4))) float f32x4;
typedef __attribute__((ext_vector_type(4))) unsigned short ushort4v;
typedef __attribute__((ext_vector_type(4))) unsigned int uint4v;
typedef unsigned short ushort;
typedef unsigned int uint;

#define B_  4
#define L_  8192
#define D_  512
#define H_  8
#define F_  65      // DK + PD
#define CF_ 520     // H * F
#define CFP_ 544    // CF padded to multiple of 32 (MFMA K)
#define KVS_ 80     // K/V head-major row stride (65 used + 15 pad)
#define EPS_ 1e-5f

// fp32 -> bf16 round-to-nearest-even
__device__ __forceinline__ ushort f2b(float f) {
    uint x = __float_as_uint(f);
    uint r = (x + 0x7FFFu + ((x >> 16) & 1u)) >> 16;
    return (ushort)r;
}
__device__ __forceinline__ float b2f(ushort u) {
    return __uint_as_float(((uint)u) << 16);
}

#define GLD16(gptr, sptr) \
    __builtin_amdgcn_global_load_lds((const __attribute__((address_space(1))) void*)(gptr), \
                                     (__attribute__((address_space(3))) void*)(sptr), 16, 0, 0)

// Packed bf16 operand layout (tile-linear LDS image):
//   one tile = 128 rows x 32 k = 4096 shorts (8 KB); element (row,k) at
//   idx = ((k>>3)&3)*1024 + row*8 + (k&7). Operand = tiles [outer][ks];
//   staging is a lane-linear contiguous 16B/lane copy.
__device__ __forceinline__ size_t pk_off(int col, int row) {
    return (size_t)(col >> 5) * 4096 + (size_t)(((col >> 3) & 3) * 1024 + row * 8 + (col & 7));
}

// ---------------- K0: cast Wq/Wk/Wv to bf16, tile-packed ----------------
__global__ __launch_bounds__(256)
void cast_w(const float* __restrict__ Wq, const float* __restrict__ Wk,
            const float* __restrict__ Wv, ushort* __restrict__ Wb)
{
    const int g = blockIdx.x * 256 + threadIdx.x;   // one 16B group each
    const int inner = g & 511;
    const int tileIdx = g >> 9;                     // (z*4+nt)*16 + ks
    const int w   = inner >> 7;
    const int row = inner & 127;
    const int ks  = tileIdx & 15;
    const int nt  = (tileIdx >> 4) & 3;
    const int z   = tileIdx >> 6;
    const float* __restrict__ src = (z == 0) ? Wq : (z == 1) ? Wk : Wv;
    const float* s = &src[(size_t)(nt * 128 + row) * D_ + ks * 32 + w * 8];
    const float4 f0 = *(const float4*)s;
    const float4 f1 = *(const float4*)(s + 4);
    short8 v;
    v[0] = (short)f2b(f0.x); v[1] = (short)f2b(f0.y);
    v[2] = (short)f2b(f0.z); v[3] = (short)f2b(f0.w);
    v[4] = (short)f2b(f1.x); v[5] = (short)f2b(f1.y);
    v[6] = (short)f2b(f1.z); v[7] = (short)f2b(f1.w);
    *(short8*)&Wb[(size_t)tileIdx * 4096 + inner * 8] = v;
}

// ---------------- K1: MFMA projection GEMM + fused LN/pos epilogue ----------------
// Double-buffered LDS, ONE __syncthreads per K-step: the barrier at step ks
// drains prefetch(ks) which was issued a full compute-phase earlier, so load
// latency hides under MFMA+cvt. Prefetch(ks+1) is issued right after the
// barrier, before compute(ks).
__global__ __launch_bounds__(256, 2)
void proj_mfma(const float* __restrict__ Xq, const float* __restrict__ Xk,
               const float* __restrict__ Xv, const ushort* __restrict__ Wb,
               const float* __restrict__ bq, const float* __restrict__ bk,
               const float* __restrict__ bv, const float* __restrict__ pos,
               const float* __restrict__ gK, const float* __restrict__ betaK,
               const float* __restrict__ gV, const float* __restrict__ betaV,
               ushort* __restrict__ Qc, ushort* __restrict__ Kh,
               ushort* __restrict__ Vh)
{
    const int x  = blockIdx.x;
    const int m0 = (((x >> 5) << 3) + (x & 7)) * 128;   // XCD swizzle
    const int n0 = ((x >> 3) & 3) * 128;
    const int z  = blockIdx.y;

    const float*  __restrict__ X    = (z == 0) ? Xq : (z == 1) ? Xk : Xv;
    const float*  __restrict__ bias = (z == 0) ? bq : (z == 1) ? bk : bv;

    const int t  = threadIdx.x;
    const int w  = t >> 6, l = t & 63;
    const int wm = (w >> 1) * 64, wn = (w & 1) * 64;
    const int lg = l >> 4, lm = l & 15;

    __shared__ __align__(16) float sAf[2][4096];   // 2 x 16 KB fp32 A tiles
    __shared__ __align__(16) short sB[2][4096];    // 2 x 8 KB bf16 B tiles

    f32x4 acc[4][4];
#pragma unroll
    for (int i = 0; i < 4; ++i)
#pragma unroll
        for (int j = 0; j < 4; ++j) acc[i][j] = (f32x4){0.f, 0.f, 0.f, 0.f};

    // A staging: LDS slot s of row r holds global half-chunk s^(r&7)
    // (pre-swizzled source, linear LDS dest).
    const int lr = l >> 3;
    const int hg = (l & 7) ^ lr;
    const float* ag[4]; int alo[4];
#pragma unroll
    for (int i = 0; i < 4; ++i) {
        const int row = (w * 4 + i) * 8 + lr;
        ag[i]  = &X[(size_t)(m0 + row) * D_ + hg * 4];
        alo[i] = (w * 4 + i) * 256;
    }

    // B staging from packed Wb: wave w copies its contiguous 2 KB slice.
    const ushort* bsrc = Wb + (size_t)((z * 4 + (n0 >> 7)) * 16) * 4096 + w * 1024 + l * 8;
    const int blo0 = w * 1024, blo1 = w * 1024 + 512;

    int a0o[4], a1o[4], bro[4];
#pragma unroll
    for (int i = 0; i < 4; ++i) {
        const int r = wm + i * 16 + lm;
        a0o[i] = r * 32 + (((lg * 2)     ^ (r & 7)) * 4);
        a1o[i] = r * 32 + (((lg * 2 + 1) ^ (r & 7)) * 4);
        bro[i] = lg * 1024 + (wn + i * 16 + lm) * 8;
    }

    auto stage = [&](int ks, int buf) {
#pragma unroll
        for (int i = 0; i < 4; ++i) GLD16(ag[i] + ks * 32, &sAf[buf][alo[i]]);
        GLD16(bsrc + (size_t)ks * 4096,       &sB[buf][blo0]);
        GLD16(bsrc + (size_t)ks * 4096 + 512, &sB[buf][blo1]);
    };

    stage(0, 0);
    int cur = 0;
#pragma unroll
    for (int ks = 0; ks < 16; ++ks) {
        __syncthreads();                    // drains stage(ks); readers safe; buf cur^1 free
        if (ks < 15) stage(ks + 1, cur ^ 1);

        short8 af[4], bfv[4];
#pragma unroll
        for (int i = 0; i < 4; ++i) {
            const f32x4 A0 = *(const f32x4*)&sAf[cur][a0o[i]];
            const f32x4 A1 = *(const f32x4*)&sAf[cur][a1o[i]];
            uint u0, u1, u2, u3;
            asm("v_cvt_pk_bf16_f32 %0, %1, %2" : "=v"(u0) : "v"(A0[0]), "v"(A0[1]));
            asm("v_cvt_pk_bf16_f32 %0, %1, %2" : "=v"(u1) : "v"(A0[2]), "v"(A0[3]));
            asm("v_cvt_pk_bf16_f32 %0, %1, %2" : "=v"(u2) : "v"(A1[0]), "v"(A1[1]));
            asm("v_cvt_pk_bf16_f32 %0, %1, %2" : "=v"(u3) : "v"(A1[2]), "v"(A1[3]));
            union { uint4v u4; short8 s8; } cv;
            cv.u4 = (uint4v){u0, u1, u2, u3};
            af[i]  = cv.s8;
            bfv[i] = *(const short8*)&sB[cur][bro[i]];
        }
#pragma unroll
        for (int mt = 0; mt < 4; ++mt)
#pragma unroll
            for (int nt = 0; nt < 4; ++nt)
                acc[mt][nt] = __builtin_amdgcn_mfma_f32_16x16x32_bf16(
                    af[mt], bfv[nt], acc[mt][nt], 0, 0, 0);

        cur ^= 1;
    }

    // -------- fused epilogue --------
    const int h = (n0 >> 6) + (w & 1);
    float bvv[4];
#pragma unroll
    for (int nt = 0; nt < 4; ++nt) bvv[nt] = bias[n0 + wn + nt * 16 + lm];

    if (z == 0) {
#pragma unroll
        for (int mt = 0; mt < 4; ++mt) {
#pragma unroll
            for (int r = 0; r < 4; ++r) {
                const int m = m0 + wm + mt * 16 + lg * 4 + r;
                const int mtile = m >> 7, rowin = m & 127;
                ushort* tb = Qc + (size_t)(mtile * 17) * 4096 + rowin * 8;
#pragma unroll
                for (int nt = 0; nt < 4; ++nt) {
                    const int col = h * F_ + 1 + nt * 16 + lm;
                    tb[pk_off(col, 0)] = f2b(acc[mt][nt][r] + bvv[nt]);
                }
                if (lm == 15) {
                    const int col = h * F_;
                    tb[pk_off(col, 0)] = f2b(pos[m]);
                }
                if (h == 7 && lm < 12) {
                    const int wreg = 1 + (lm >> 2);
                    const int e2 = (lm & 3) * 2;
                    *(uint*)&tb[(size_t)16 * 4096 + wreg * 1024 + e2] = 0u;
                }
            }
        }
    } else {
        const float* gp = (z == 1) ? gK : gV;
        const float* bp = (z == 1) ? betaK : betaV;
        ushort* Oh = (z == 1) ? Kh : Vh;
        float gg[4], bb2[4];
#pragma unroll
        for (int nt = 0; nt < 4; ++nt) {
            gg[nt]  = gp[h * 64 + nt * 16 + lm];
            bb2[nt] = bp[h * 64 + nt * 16 + lm];
        }
#pragma unroll
        for (int mt = 0; mt < 4; ++mt) {
#pragma unroll
            for (int r = 0; r < 4; ++r) {
                float v0 = acc[mt][0][r] + bvv[0];
                float v1 = acc[mt][1][r] + bvv[1];
                float v2 = acc[mt][2][r] + bvv[2];
                float v3 = acc[mt][3][r] + bvv[3];
                float s = v0 + v1 + v2 + v3;
                float q = v0 * v0 + v1 * v1 + v2 * v2 + v3 * v3;
                s += __shfl_xor(s, 1); s += __shfl_xor(s, 2);
                s += __shfl_xor(s, 4); s += __shfl_xor(s, 8);
                q += __shfl_xor(q, 1); q += __shfl_xor(q, 2);
                q += __shfl_xor(q, 4); q += __shfl_xor(q, 8);
                const float mean = s * (1.f / 64.f);
                const float var = q * (1.f / 64.f) - mean * mean;
                const float rs = rsqrtf(var + EPS_);
                const int m = m0 + wm + mt * 16 + lg * 4 + r;
                const int bb = m >> 13, ll = m & 8191;
                ushort* row = Oh + ((size_t)(bb * H_ + h) * L_ + ll) * KVS_;
                row[1 + 0 * 16 + lm] = f2b((v0 - mean) * rs * gg[0] + bb2[0]);
                row[1 + 1 * 16 + lm] = f2b((v1 - mean) * rs * gg[1] + bb2[1]);
                row[1 + 2 * 16 + lm] = f2b((v2 - mean) * rs * gg[2] + bb2[2]);
                row[1 + 3 * 16 + lm] = f2b((v3 - mean) * rs * gg[3] + bb2[3]);
                if (lm == 15) row[0] = f2b(pos[m]);
                else          row[F_ + lm] = 0;
            }
        }
    }
}

// ---------------- K3: attn accumulation: sum_l K[l][d]*V[l][e] ----------------
__global__ __launch_bounds__(256)
void attn_accum(const ushort* __restrict__ Kh, const ushort* __restrict__ Vh,
                float* __restrict__ attn_acc)
{
    const int s = blockIdx.x;
    const int h = blockIdx.y;
    const int b = blockIdx.z;
    const int t = threadIdx.x;

    __shared__ __align__(16) float Ks[64][84];
    __shared__ __align__(16) float Vs[64][84];

    const size_t base = ((size_t)(b * H_ + h) * L_ + s * 512) * KVS_;

    float acc[5][5];
#pragma unroll
    for (int i = 0; i < 5; ++i)
#pragma unroll
        for (int j = 0; j < 5; ++j) acc[i][j] = 0.f;

    const int dg = t / 13, eg = t % 13;
    const bool act = (t < 169);
    const int d0 = dg * 5, e0 = eg * 5;

    for (int c = 0; c < 8; ++c) {
#pragma unroll
        for (int i = 0; i < 3; ++i) {
            const int slot = t + i * 256;
            if (slot < 640) {
                const int r = slot / 10;
                const int cc = (slot - r * 10) * 8;
                const size_t g = base + (size_t)(c * 64 + r) * KVS_ + cc;
                const short8 kv = *(const short8*)(const void*)&Kh[g];
                const short8 vv = *(const short8*)(const void*)&Vh[g];
                float* kd = &Ks[r][cc];
                float* vd = &Vs[r][cc];
#pragma unroll
                for (int e = 0; e < 8; ++e) {
                    kd[e] = b2f((ushort)kv[e]);
                    vd[e] = b2f((ushort)vv[e]);
                }
            }
        }
        __syncthreads();
        if (act) {
#pragma unroll 2
            for (int l = 0; l < 64; ++l) {
                float kf[5], vf[5];
#pragma unroll
                for (int i = 0; i < 5; ++i) kf[i] = Ks[l][d0 + i];
#pragma unroll
                for (int j = 0; j < 5; ++j) vf[j] = Vs[l][e0 + j];
#pragma unroll
                for (int i = 0; i < 5; ++i)
#pragma unroll
                    for (int j = 0; j < 5; ++j)
                        acc[i][j] = fmaf(kf[i], vf[j], acc[i][j]);
            }
        }
        __syncthreads();
    }

    if (act) {
        float* dst = attn_acc + (size_t)(b * H_ + h) * (F_ * F_);
#pragma unroll
        for (int i = 0; i < 5; ++i)
#pragma unroll
            for (int j = 0; j < 5; ++j)
                atomicAdd(&dst[(d0 + i) * F_ + (e0 + j)], acc[i][j]);
    }
}

// ---------------- K4: attn/L -> d_out; Gt = packed (attn @ fcW_h^T)^T bf16 ----------------
__global__ __launch_bounds__(256)
void attn_fin_G(const float* __restrict__ attn_acc, const float* __restrict__ fcW,
                float* __restrict__ attn_out, ushort* __restrict__ Gt)
{
    const int nc = blockIdx.x;
    const int h = blockIdx.y;
    const int b = blockIdx.z;
    const int t = threadIdx.x;

    __shared__ float S[F_][F_];
    __shared__ float Wl[64][F_];

    const float inv = 1.0f / (float)L_;
    const float* __restrict__ src = attn_acc + (size_t)(b * H_ + h) * F_ * F_;
    for (int idx = t; idx < F_ * F_; idx += 256) {
        const float v = src[idx] * inv;
        S[idx / F_][idx % F_] = v;
        if (nc == 0) attn_out[(size_t)(b * H_ + h) * F_ * F_ + idx] = v;
    }
    for (int idx = t; idx < 64 * F_; idx += 256) {
        const int j = idx / F_;
        const int e = idx - j * F_;
        Wl[j][e] = fcW[(size_t)(nc * 64 + j) * CF_ + h * F_ + e];
    }
    __syncthreads();

    for (int idx = t; idx < F_ * 64; idx += 256) {
        const int d = idx >> 6;
        const int j = idx & 63;
        float g = 0.f;
#pragma unroll 5
        for (int e = 0; e < F_; ++e) g = fmaf(S[d][e], Wl[j][e], g);
        const int jg = nc * 64 + j;
        const int col = h * F_ + d;
        Gt[(size_t)((b * 4 + (jg >> 7)) * 17) * 4096 + (jg & 127) * 8 + pk_off(col, 0)] = f2b(g);
    }
    if (h == 7) {
        for (int i2 = t; i2 < 64 * 24; i2 += 256) {
            const int j = i2 / 24;
            const int col = CF_ + (i2 % 24);
            const int jg = nc * 64 + j;
            Gt[(size_t)((b * 4 + (jg >> 7)) * 17) * 4096 + (jg & 127) * 8 + pk_off(col, 0)] = 0;
        }
    }
}

// ---------------- K5: att_output = Qc @ Gt^T + fcb (packed operands, dbuf) --------
__global__ __launch_bounds__(256, 2)
void out_mfma(const ushort* __restrict__ Qc, const ushort* __restrict__ Gt,
              const float* __restrict__ fcb, float* __restrict__ out)
{
    const int x  = blockIdx.x;
    const int m0 = (((x >> 5) << 3) + (x & 7)) * 128;
    const int n0 = ((x >> 3) & 3) * 128;
    const int b  = blockIdx.z;
    const int t  = threadIdx.x;
    const int w  = t >> 6, l = t & 63;
    const int wm = (w >> 1) * 64, wn = (w & 1) * 64;
    const int lg = l >> 4, lm = l & 15;

    __shared__ __align__(16) short sA[2][4096];
    __shared__ __align__(16) short sB[2][4096];

    f32x4 acc[4][4];
#pragma unroll
    for (int i = 0; i < 4; ++i)
#pragma unroll
        for (int j = 0; j < 4; ++j) acc[i][j] = (f32x4){0.f, 0.f, 0.f, 0.f};

    const int mtA = (b * L_ + m0) >> 7;
    const ushort* asrc = Qc + (size_t)(mtA * 17) * 4096 + w * 1024 + l * 8;
    const ushort* bsrc = Gt + (size_t)((b * 4 + (n0 >> 7)) * 17) * 4096 + w * 1024 + l * 8;
    const int lo0 = w * 1024, lo1 = w * 1024 + 512;

    int aro[4], bro[4];
#pragma unroll
    for (int i = 0; i < 4; ++i) {
        aro[i] = lg * 1024 + (wm + i * 16 + lm) * 8;
        bro[i] = lg * 1024 + (wn + i * 16 + lm) * 8;
    }

    auto stage = [&](int ks, int buf) {
        GLD16(asrc + (size_t)ks * 4096,       &sA[buf][lo0]);
        GLD16(asrc + (size_t)ks * 4096 + 512, &sA[buf][lo1]);
        GLD16(bsrc + (size_t)ks * 4096,       &sB[buf][lo0]);
        GLD16(bsrc + (size_t)ks * 4096 + 512, &sB[buf][lo1]);
    };

    stage(0, 0);
    int cur = 0;
#pragma unroll
    for (int ks = 0; ks < 17; ++ks) {
        __syncthreads();
        if (ks < 16) stage(ks + 1, cur ^ 1);

        short8 af[4], bfv[4];
#pragma unroll
        for (int i = 0; i < 4; ++i) {
            af[i]  = *(const short8*)&sA[cur][aro[i]];
            bfv[i] = *(const short8*)&sB[cur][bro[i]];
        }
#pragma unroll
        for (int mt = 0; mt < 4; ++mt)
#pragma unroll
            for (int nt = 0; nt < 4; ++nt)
                acc[mt][nt] = __builtin_amdgcn_mfma_f32_16x16x32_bf16(
                    af[mt], bfv[nt], acc[mt][nt], 0, 0, 0);

        cur ^= 1;
    }

    float bvv[4];
#pragma unroll
    for (int nt = 0; nt < 4; ++nt) bvv[nt] = fcb[n0 + wn + nt * 16 + lm];

#pragma unroll
    for (int mt = 0; mt < 4; ++mt) {
#pragma unroll
        for (int r = 0; r < 4; ++r) {
            const int row = m0 + wm + mt * 16 + lg * 4 + r;
            float* orow = out + ((size_t)b * L_ + row) * D_;
#pragma unroll
            for (int nt = 0; nt < 4; ++nt)
                orow[n0 + wn + nt * 16 + lm] = acc[mt][nt][r] + bvv[nt];
        }
    }
}

extern "C" void kernel_launch(void* const* d_in, const int* in_sizes, int n_in,
                              void* d_out, int out_size, void* d_ws, size_t ws_size,
                              hipStream_t stream)
{
    const float* query = (const float*)d_in[0];
    const float* key   = (const float*)d_in[1];
    const float* value = (const float*)d_in[2];
    const float* pos   = (const float*)d_in[3];
    const float* Wq    = (const float*)d_in[4];
    const float* bq    = (const float*)d_in[5];
    const float* Wk    = (const float*)d_in[6];
    const float* bk    = (const float*)d_in[7];
    const float* Wv    = (const float*)d_in[8];
    const float* bv    = (const float*)d_in[9];
    const float* gK    = (const float*)d_in[10];
    const float* betaK = (const float*)d_in[11];
    const float* gV    = (const float*)d_in[12];
    const float* betaV = (const float*)d_in[13];
    const float* fcW   = (const float*)d_in[14];
    const float* fcb   = (const float*)d_in[15];

    char* ws = (char*)d_ws;
    ushort* Qc       = (ushort*)(ws + 0);            // 256x17 packed tiles = 35651584 B
    ushort* Kh       = (ushort*)(ws + 35651584);     // [4][8][8192][80] bf16
    ushort* Vh       = (ushort*)(ws + 77594624);     // [4][8][8192][80] bf16
    ushort* Wb       = (ushort*)(ws + 119537664);    // 12x16 packed tiles = 1572864 B
    float*  attn_acc = (float*) (ws + 121110528);    // [4][8][65][65] fp32
    ushort* Gt       = (ushort*)(ws + 121651328);    // 16x17 packed tiles = 2228224 B

    float* att_out  = (float*)d_out;                 // [4][8192][512]
    float* attn_out = att_out + 16777216;            // [4][8][65][65]

    hipMemsetAsync(attn_acc, 0, (size_t)135200 * sizeof(float), stream);

    cast_w<<<dim3(384), 256, 0, stream>>>(Wq, Wk, Wv, Wb);

    proj_mfma<<<dim3(1024, 3), 256, 0, stream>>>(
        query, key, value, Wb, bq, bk, bv, pos,
        gK, betaK, gV, betaV, Qc, Kh, Vh);

    attn_accum<<<dim3(16, 8, 4), 256, 0, stream>>>(Kh, Vh, attn_acc);

    attn_fin_G<<<dim3(8, 8, 4), 256, 0, stream>>>(attn_acc, fcW, attn_out, Gt);

    out_mfma<<<dim3(256, 1, 4), 256, 0, stream>>>(Qc, Gt, fcb, att_out);
}

// Round 4
// 460.261 us; speedup vs baseline: 1.1407x; 1.0837x over previous
//
#include <hip/hip_runtime.h>

typedef __attribute__((ext_vector_type(8))) short short8;
typedef __attribute__((ext_vector_type(4))) float f32x4;
typedef __attribute__((ext_vector_type(4))) unsigned short ushort4v;
typedef __attribute__((ext_vector_type(4))) unsigned int uint4v;
typedef unsigned short ushort;
typedef unsigned int uint;

#define B_  4
#define L_  8192
#define D_  512
#define H_  8
#define F_  65      // DK + PD
#define CF_ 520     // H * F
#define CFP_ 544    // CF padded to multiple of 32 (MFMA K)
#define KVS_ 80     // K/V head-major row stride (65 used + 15 pad)
#define EPS_ 1e-5f

// fp32 -> bf16 round-to-nearest-even
__device__ __forceinline__ ushort f2b(float f) {
    uint x = __float_as_uint(f);
    uint r = (x + 0x7FFFu + ((x >> 16) & 1u)) >> 16;
    return (ushort)r;
}
__device__ __forceinline__ float b2f(ushort u) {
    return __uint_as_float(((uint)u) << 16);
}

#define GLD16(gptr, sptr) \
    __builtin_amdgcn_global_load_lds((const __attribute__((address_space(1))) void*)(gptr), \
                                     (__attribute__((address_space(3))) void*)(sptr), 16, 0, 0)

// Packed bf16 operand layout (tile-linear LDS image):
//   one tile = 128 rows x 32 k = 4096 shorts (8 KB); element (row,k) at
//   idx = ((k>>3)&3)*1024 + row*8 + (k&7). Operand = tiles [outer][ks];
//   staging is a lane-linear contiguous 16B/lane copy.
__device__ __forceinline__ size_t pk_off(int col, int row) {
    return (size_t)(col >> 5) * 4096 + (size_t)(((col >> 3) & 3) * 1024 + row * 8 + (col & 7));
}

// ---------------- K0: cast Wq/Wk/Wv to bf16, tile-packed ----------------
__global__ __launch_bounds__(256)
void cast_w(const float* __restrict__ Wq, const float* __restrict__ Wk,
            const float* __restrict__ Wv, ushort* __restrict__ Wb)
{
    const int g = blockIdx.x * 256 + threadIdx.x;   // one 16B group each
    const int inner = g & 511;
    const int tileIdx = g >> 9;                     // (z*4+nt)*16 + ks
    const int w   = inner >> 7;
    const int row = inner & 127;
    const int ks  = tileIdx & 15;
    const int nt  = (tileIdx >> 4) & 3;
    const int z   = tileIdx >> 6;
    const float* __restrict__ src = (z == 0) ? Wq : (z == 1) ? Wk : Wv;
    const float* s = &src[(size_t)(nt * 128 + row) * D_ + ks * 32 + w * 8];
    const float4 f0 = *(const float4*)s;
    const float4 f1 = *(const float4*)(s + 4);
    short8 v;
    v[0] = (short)f2b(f0.x); v[1] = (short)f2b(f0.y);
    v[2] = (short)f2b(f0.z); v[3] = (short)f2b(f0.w);
    v[4] = (short)f2b(f1.x); v[5] = (short)f2b(f1.y);
    v[6] = (short)f2b(f1.z); v[7] = (short)f2b(f1.w);
    *(short8*)&Wb[(size_t)tileIdx * 4096 + inner * 8] = v;
}

// ---------------- K1: MFMA projection GEMM + fused LN/pos epilogue ----------------
// Tile 128(M) x 256(N): each block reads its A-slice for 2 n-halves instead of 4
// (logical A traffic halved), 32 MFMA per wave per K-step. Double-buffered LDS,
// one __syncthreads per K-step. Wave w: rows (w>>1)*64.., cols (w&1)*128.. (2 heads).
__global__ __launch_bounds__(256, 2)
void proj_mfma(const float* __restrict__ Xq, const float* __restrict__ Xk,
               const float* __restrict__ Xv, const ushort* __restrict__ Wb,
               const float* __restrict__ bq, const float* __restrict__ bk,
               const float* __restrict__ bv, const float* __restrict__ pos,
               const float* __restrict__ gK, const float* __restrict__ betaK,
               const float* __restrict__ gV, const float* __restrict__ betaV,
               ushort* __restrict__ Qc, ushort* __restrict__ Kh,
               ushort* __restrict__ Vh)
{
    const int x  = blockIdx.x;                           // [0,512)
    const int m0 = (((x >> 4) << 3) + (x & 7)) * 128;    // XCD swizzle: both n-halves
    const int nh = (x >> 3) & 1;                         // of same m land on same XCD
    const int n0 = nh * 256;
    const int z  = blockIdx.y;

    const float*  __restrict__ X    = (z == 0) ? Xq : (z == 1) ? Xk : Xv;
    const float*  __restrict__ bias = (z == 0) ? bq : (z == 1) ? bk : bv;

    const int t  = threadIdx.x;
    const int w  = t >> 6, l = t & 63;
    const int wm = (w >> 1) * 64, wn = (w & 1) * 128;
    const int lg = l >> 4, lm = l & 15;

    __shared__ __align__(16) float sAf[2][4096];   // 2 x 16 KB fp32 A tiles (swizzled slots)
    __shared__ __align__(16) short sB[2][8192];    // 2 x 16 KB bf16 B (two packed 128-tiles)

    f32x4 acc[4][8];
#pragma unroll
    for (int i = 0; i < 4; ++i)
#pragma unroll
        for (int j = 0; j < 8; ++j) acc[i][j] = (f32x4){0.f, 0.f, 0.f, 0.f};

    // A staging: LDS slot s of row r holds global half-chunk s^(r&7)
    // (pre-swizzled source, linear LDS dest).
    const int lr = l >> 3;
    const int hg = (l & 7) ^ lr;
    const float* ag[4]; int alo[4];
#pragma unroll
    for (int i = 0; i < 4; ++i) {
        const int row = (w * 4 + i) * 8 + lr;
        ag[i]  = &X[(size_t)(m0 + row) * D_ + hg * 4];
        alo[i] = (w * 4 + i) * 256;
    }

    // B staging from packed Wb: two 128-col tiles per K-step.
    const ushort* bsrc0 = Wb + (size_t)((z * 4 + nh * 2) * 16) * 4096 + w * 1024 + l * 8;
    const ushort* bsrc1 = bsrc0 + (size_t)16 * 4096;     // next n-tile's 16-ks block
    const int blo0 = w * 1024, blo1 = w * 1024 + 512;

    int a0o[4], a1o[4], bro[8];
#pragma unroll
    for (int i = 0; i < 4; ++i) {
        const int r = wm + i * 16 + lm;
        a0o[i] = r * 32 + (((lg * 2)     ^ (r & 7)) * 4);
        a1o[i] = r * 32 + (((lg * 2 + 1) ^ (r & 7)) * 4);
    }
#pragma unroll
    for (int i = 0; i < 8; ++i) {
        const int col = wn + i * 16 + lm;                // [0,256)
        bro[i] = (col >> 7) * 4096 + lg * 1024 + (col & 127) * 8;
    }

    auto stage = [&](int ks, int buf) {
#pragma unroll
        for (int i = 0; i < 4; ++i) GLD16(ag[i] + ks * 32, &sAf[buf][alo[i]]);
        GLD16(bsrc0 + (size_t)ks * 4096,       &sB[buf][blo0]);
        GLD16(bsrc0 + (size_t)ks * 4096 + 512, &sB[buf][blo1]);
        GLD16(bsrc1 + (size_t)ks * 4096,       &sB[buf][4096 + blo0]);
        GLD16(bsrc1 + (size_t)ks * 4096 + 512, &sB[buf][4096 + blo1]);
    };

    stage(0, 0);
    int cur = 0;
#pragma unroll
    for (int ks = 0; ks < 16; ++ks) {
        __syncthreads();                    // drains stage(ks); buf cur^1 free
        if (ks < 15) stage(ks + 1, cur ^ 1);

        short8 af[4], bfv[8];
#pragma unroll
        for (int i = 0; i < 4; ++i) {
            const f32x4 A0 = *(const f32x4*)&sAf[cur][a0o[i]];
            const f32x4 A1 = *(const f32x4*)&sAf[cur][a1o[i]];
            uint u0, u1, u2, u3;
            asm("v_cvt_pk_bf16_f32 %0, %1, %2" : "=v"(u0) : "v"(A0[0]), "v"(A0[1]));
            asm("v_cvt_pk_bf16_f32 %0, %1, %2" : "=v"(u1) : "v"(A0[2]), "v"(A0[3]));
            asm("v_cvt_pk_bf16_f32 %0, %1, %2" : "=v"(u2) : "v"(A1[0]), "v"(A1[1]));
            asm("v_cvt_pk_bf16_f32 %0, %1, %2" : "=v"(u3) : "v"(A1[2]), "v"(A1[3]));
            union { uint4v u4; short8 s8; } cv;
            cv.u4 = (uint4v){u0, u1, u2, u3};
            af[i] = cv.s8;
        }
#pragma unroll
        for (int i = 0; i < 8; ++i) bfv[i] = *(const short8*)&sB[cur][bro[i]];
#pragma unroll
        for (int mt = 0; mt < 4; ++mt)
#pragma unroll
            for (int nt = 0; nt < 8; ++nt)
                acc[mt][nt] = __builtin_amdgcn_mfma_f32_16x16x32_bf16(
                    af[mt], bfv[nt], acc[mt][nt], 0, 0, 0);

        cur ^= 1;
    }

    // -------- fused epilogue (wave owns 64 rows x 2 heads) --------
    const int h0 = (n0 + wn) >> 6;          // even; wave covers heads h0, h0+1
    float bvv[8];
#pragma unroll
    for (int nt = 0; nt < 8; ++nt) bvv[nt] = bias[n0 + wn + nt * 16 + lm];

    if (z == 0) {
#pragma unroll
        for (int mt = 0; mt < 4; ++mt) {
#pragma unroll
            for (int r = 0; r < 4; ++r) {
                const int m = m0 + wm + mt * 16 + lg * 4 + r;
                const int mtile = m >> 7, rowin = m & 127;
                ushort* tb = Qc + (size_t)(mtile * 17) * 4096 + rowin * 8;
#pragma unroll
                for (int nt = 0; nt < 8; ++nt) {
                    const int col = (h0 + (nt >> 2)) * F_ + 1 + (nt & 3) * 16 + lm;
                    tb[pk_off(col, 0)] = f2b(acc[mt][nt][r] + bvv[nt]);
                }
                if (lm == 15) {
                    tb[pk_off(h0 * F_, 0)]       = f2b(pos[m]);
                    tb[pk_off((h0 + 1) * F_, 0)] = f2b(pos[m]);
                }
                if (h0 == 6 && lm < 12) {
                    const int wreg = 1 + (lm >> 2);
                    const int e2 = (lm & 3) * 2;
                    *(uint*)&tb[(size_t)16 * 4096 + wreg * 1024 + e2] = 0u;
                }
            }
        }
    } else {
        const float* gp = (z == 1) ? gK : gV;
        const float* bp = (z == 1) ? betaK : betaV;
        ushort* Oh = (z == 1) ? Kh : Vh;
        float gg[8], bb2[8];
#pragma unroll
        for (int nt = 0; nt < 8; ++nt) {
            const int idx = (h0 + (nt >> 2)) * 64 + (nt & 3) * 16 + lm;
            gg[nt]  = gp[idx];
            bb2[nt] = bp[idx];
        }
#pragma unroll
        for (int mt = 0; mt < 4; ++mt) {
#pragma unroll
            for (int r = 0; r < 4; ++r) {
                const int m = m0 + wm + mt * 16 + lg * 4 + r;
                const int bb = m >> 13, ll = m & 8191;
#pragma unroll
                for (int g = 0; g < 2; ++g) {
                    const float v0 = acc[mt][g * 4 + 0][r] + bvv[g * 4 + 0];
                    const float v1 = acc[mt][g * 4 + 1][r] + bvv[g * 4 + 1];
                    const float v2 = acc[mt][g * 4 + 2][r] + bvv[g * 4 + 2];
                    const float v3 = acc[mt][g * 4 + 3][r] + bvv[g * 4 + 3];
                    float s = v0 + v1 + v2 + v3;
                    float q = v0 * v0 + v1 * v1 + v2 * v2 + v3 * v3;
                    s += __shfl_xor(s, 1); s += __shfl_xor(s, 2);
                    s += __shfl_xor(s, 4); s += __shfl_xor(s, 8);
                    q += __shfl_xor(q, 1); q += __shfl_xor(q, 2);
                    q += __shfl_xor(q, 4); q += __shfl_xor(q, 8);
                    const float mean = s * (1.f / 64.f);
                    const float var = q * (1.f / 64.f) - mean * mean;
                    const float rs = rsqrtf(var + EPS_);
                    const int h = h0 + g;
                    ushort* row = Oh + ((size_t)(bb * H_ + h) * L_ + ll) * KVS_;
                    row[1 + 0 * 16 + lm] = f2b((v0 - mean) * rs * gg[g * 4 + 0] + bb2[g * 4 + 0]);
                    row[1 + 1 * 16 + lm] = f2b((v1 - mean) * rs * gg[g * 4 + 1] + bb2[g * 4 + 1]);
                    row[1 + 2 * 16 + lm] = f2b((v2 - mean) * rs * gg[g * 4 + 2] + bb2[g * 4 + 2]);
                    row[1 + 3 * 16 + lm] = f2b((v3 - mean) * rs * gg[g * 4 + 3] + bb2[g * 4 + 3]);
                    if (lm == 15) row[0] = f2b(pos[m]);
                    else          row[F_ + lm] = 0;
                }
            }
        }
    }
}

// ---------------- K3: attn accumulation: sum_l K[l][d]*V[l][e] ----------------
__global__ __launch_bounds__(256)
void attn_accum(const ushort* __restrict__ Kh, const ushort* __restrict__ Vh,
                float* __restrict__ attn_acc)
{
    const int s = blockIdx.x;
    const int h = blockIdx.y;
    const int b = blockIdx.z;
    const int t = threadIdx.x;

    __shared__ __align__(16) float Ks[64][84];
    __shared__ __align__(16) float Vs[64][84];

    const size_t base = ((size_t)(b * H_ + h) * L_ + s * 512) * KVS_;

    float acc[5][5];
#pragma unroll
    for (int i = 0; i < 5; ++i)
#pragma unroll
        for (int j = 0; j < 5; ++j) acc[i][j] = 0.f;

    const int dg = t / 13, eg = t % 13;
    const bool act = (t < 169);
    const int d0 = dg * 5, e0 = eg * 5;

    for (int c = 0; c < 8; ++c) {
#pragma unroll
        for (int i = 0; i < 3; ++i) {
            const int slot = t + i * 256;
            if (slot < 640) {
                const int r = slot / 10;
                const int cc = (slot - r * 10) * 8;
                const size_t g = base + (size_t)(c * 64 + r) * KVS_ + cc;
                const short8 kv = *(const short8*)(const void*)&Kh[g];
                const short8 vv = *(const short8*)(const void*)&Vh[g];
                float* kd = &Ks[r][cc];
                float* vd = &Vs[r][cc];
#pragma unroll
                for (int e = 0; e < 8; ++e) {
                    kd[e] = b2f((ushort)kv[e]);
                    vd[e] = b2f((ushort)vv[e]);
                }
            }
        }
        __syncthreads();
        if (act) {
#pragma unroll 2
            for (int l = 0; l < 64; ++l) {
                float kf[5], vf[5];
#pragma unroll
                for (int i = 0; i < 5; ++i) kf[i] = Ks[l][d0 + i];
#pragma unroll
                for (int j = 0; j < 5; ++j) vf[j] = Vs[l][e0 + j];
#pragma unroll
                for (int i = 0; i < 5; ++i)
#pragma unroll
                    for (int j = 0; j < 5; ++j)
                        acc[i][j] = fmaf(kf[i], vf[j], acc[i][j]);
            }
        }
        __syncthreads();
    }

    if (act) {
        float* dst = attn_acc + (size_t)(b * H_ + h) * (F_ * F_);
#pragma unroll
        for (int i = 0; i < 5; ++i)
#pragma unroll
            for (int j = 0; j < 5; ++j)
                atomicAdd(&dst[(d0 + i) * F_ + (e0 + j)], acc[i][j]);
    }
}

// ---------------- K4: attn/L -> d_out; Gt = packed (attn @ fcW_h^T)^T bf16 ----------------
__global__ __launch_bounds__(256)
void attn_fin_G(const float* __restrict__ attn_acc, const float* __restrict__ fcW,
                float* __restrict__ attn_out, ushort* __restrict__ Gt)
{
    const int nc = blockIdx.x;
    const int h = blockIdx.y;
    const int b = blockIdx.z;
    const int t = threadIdx.x;

    __shared__ float S[F_][F_];
    __shared__ float Wl[64][F_];

    const float inv = 1.0f / (float)L_;
    const float* __restrict__ src = attn_acc + (size_t)(b * H_ + h) * F_ * F_;
    for (int idx = t; idx < F_ * F_; idx += 256) {
        const float v = src[idx] * inv;
        S[idx / F_][idx % F_] = v;
        if (nc == 0) attn_out[(size_t)(b * H_ + h) * F_ * F_ + idx] = v;
    }
    for (int idx = t; idx < 64 * F_; idx += 256) {
        const int j = idx / F_;
        const int e = idx - j * F_;
        Wl[j][e] = fcW[(size_t)(nc * 64 + j) * CF_ + h * F_ + e];
    }
    __syncthreads();

    for (int idx = t; idx < F_ * 64; idx += 256) {
        const int d = idx >> 6;
        const int j = idx & 63;
        float g = 0.f;
#pragma unroll 5
        for (int e = 0; e < F_; ++e) g = fmaf(S[d][e], Wl[j][e], g);
        const int jg = nc * 64 + j;
        const int col = h * F_ + d;
        Gt[(size_t)((b * 4 + (jg >> 7)) * 17) * 4096 + (jg & 127) * 8 + pk_off(col, 0)] = f2b(g);
    }
    if (h == 7) {
        for (int i2 = t; i2 < 64 * 24; i2 += 256) {
            const int j = i2 / 24;
            const int col = CF_ + (i2 % 24);
            const int jg = nc * 64 + j;
            Gt[(size_t)((b * 4 + (jg >> 7)) * 17) * 4096 + (jg & 127) * 8 + pk_off(col, 0)] = 0;
        }
    }
}

// ---------------- K5: att_output = Qc @ Gt^T + fcb (128x256 tile, dbuf) --------
__global__ __launch_bounds__(256, 2)
void out_mfma(const ushort* __restrict__ Qc, const ushort* __restrict__ Gt,
              const float* __restrict__ fcb, float* __restrict__ out)
{
    const int x  = blockIdx.x;                           // [0,128)
    const int m0 = (((x >> 4) << 3) + (x & 7)) * 128;
    const int nh = (x >> 3) & 1;
    const int n0 = nh * 256;
    const int b  = blockIdx.z;
    const int t  = threadIdx.x;
    const int w  = t >> 6, l = t & 63;
    const int wm = (w >> 1) * 64, wn = (w & 1) * 128;
    const int lg = l >> 4, lm = l & 15;

    __shared__ __align__(16) short sA[2][4096];
    __shared__ __align__(16) short sB[2][8192];

    f32x4 acc[4][8];
#pragma unroll
    for (int i = 0; i < 4; ++i)
#pragma unroll
        for (int j = 0; j < 8; ++j) acc[i][j] = (f32x4){0.f, 0.f, 0.f, 0.f};

    const int mtA = (b * L_ + m0) >> 7;
    const ushort* asrc  = Qc + (size_t)(mtA * 17) * 4096 + w * 1024 + l * 8;
    const ushort* bsrc0 = Gt + (size_t)((b * 4 + nh * 2) * 17) * 4096 + w * 1024 + l * 8;
    const ushort* bsrc1 = bsrc0 + (size_t)17 * 4096;
    const int lo0 = w * 1024, lo1 = w * 1024 + 512;

    int aro[4], bro[8];
#pragma unroll
    for (int i = 0; i < 4; ++i)
        aro[i] = lg * 1024 + (wm + i * 16 + lm) * 8;
#pragma unroll
    for (int i = 0; i < 8; ++i) {
        const int col = wn + i * 16 + lm;
        bro[i] = (col >> 7) * 4096 + lg * 1024 + (col & 127) * 8;
    }

    auto stage = [&](int ks, int buf) {
        GLD16(asrc  + (size_t)ks * 4096,       &sA[buf][lo0]);
        GLD16(asrc  + (size_t)ks * 4096 + 512, &sA[buf][lo1]);
        GLD16(bsrc0 + (size_t)ks * 4096,       &sB[buf][lo0]);
        GLD16(bsrc0 + (size_t)ks * 4096 + 512, &sB[buf][lo1]);
        GLD16(bsrc1 + (size_t)ks * 4096,       &sB[buf][4096 + lo0]);
        GLD16(bsrc1 + (size_t)ks * 4096 + 512, &sB[buf][4096 + lo1]);
    };

    stage(0, 0);
    int cur = 0;
#pragma unroll
    for (int ks = 0; ks < 17; ++ks) {
        __syncthreads();
        if (ks < 16) stage(ks + 1, cur ^ 1);

        short8 af[4], bfv[8];
#pragma unroll
        for (int i = 0; i < 4; ++i) af[i]  = *(const short8*)&sA[cur][aro[i]];
#pragma unroll
        for (int i = 0; i < 8; ++i) bfv[i] = *(const short8*)&sB[cur][bro[i]];
#pragma unroll
        for (int mt = 0; mt < 4; ++mt)
#pragma unroll
            for (int nt = 0; nt < 8; ++nt)
                acc[mt][nt] = __builtin_amdgcn_mfma_f32_16x16x32_bf16(
                    af[mt], bfv[nt], acc[mt][nt], 0, 0, 0);

        cur ^= 1;
    }

    float bvv[8];
#pragma unroll
    for (int nt = 0; nt < 8; ++nt) bvv[nt] = fcb[n0 + wn + nt * 16 + lm];

#pragma unroll
    for (int mt = 0; mt < 4; ++mt) {
#pragma unroll
        for (int r = 0; r < 4; ++r) {
            const int row = m0 + wm + mt * 16 + lg * 4 + r;
            float* orow = out + ((size_t)b * L_ + row) * D_;
#pragma unroll
            for (int nt = 0; nt < 8; ++nt)
                orow[n0 + wn + nt * 16 + lm] = acc[mt][nt][r] + bvv[nt];
        }
    }
}

extern "C" void kernel_launch(void* const* d_in, const int* in_sizes, int n_in,
                              void* d_out, int out_size, void* d_ws, size_t ws_size,
                              hipStream_t stream)
{
    const float* query = (const float*)d_in[0];
    const float* key   = (const float*)d_in[1];
    const float* value = (const float*)d_in[2];
    const float* pos   = (const float*)d_in[3];
    const float* Wq    = (const float*)d_in[4];
    const float* bq    = (const float*)d_in[5];
    const float* Wk    = (const float*)d_in[6];
    const float* bk    = (const float*)d_in[7];
    const float* Wv    = (const float*)d_in[8];
    const float* bv    = (const float*)d_in[9];
    const float* gK    = (const float*)d_in[10];
    const float* betaK = (const float*)d_in[11];
    const float* gV    = (const float*)d_in[12];
    const float* betaV = (const float*)d_in[13];
    const float* fcW   = (const float*)d_in[14];
    const float* fcb   = (const float*)d_in[15];

    char* ws = (char*)d_ws;
    ushort* Qc       = (ushort*)(ws + 0);            // 256x17 packed tiles = 35651584 B
    ushort* Kh       = (ushort*)(ws + 35651584);     // [4][8][8192][80] bf16
    ushort* Vh       = (ushort*)(ws + 77594624);     // [4][8][8192][80] bf16
    ushort* Wb       = (ushort*)(ws + 119537664);    // 12x16 packed tiles = 1572864 B
    float*  attn_acc = (float*) (ws + 121110528);    // [4][8][65][65] fp32
    ushort* Gt       = (ushort*)(ws + 121651328);    // 16x17 packed tiles = 2228224 B

    float* att_out  = (float*)d_out;                 // [4][8192][512]
    float* attn_out = att_out + 16777216;            // [4][8][65][65]

    hipMemsetAsync(attn_acc, 0, (size_t)135200 * sizeof(float), stream);

    cast_w<<<dim3(384), 256, 0, stream>>>(Wq, Wk, Wv, Wb);

    proj_mfma<<<dim3(512, 3), 256, 0, stream>>>(
        query, key, value, Wb, bq, bk, bv, pos,
        gK, betaK, gV, betaV, Qc, Kh, Vh);

    attn_accum<<<dim3(16, 8, 4), 256, 0, stream>>>(Kh, Vh, attn_acc);

    attn_fin_G<<<dim3(8, 8, 4), 256, 0, stream>>>(attn_acc, fcW, attn_out, Gt);

    out_mfma<<<dim3(128, 1, 4), 256, 0, stream>>>(Qc, Gt, fcb, att_out);
}